// Round 9
// baseline (94.816 us; speedup 1.0000x reference)
//
#include <hip/hip_runtime.h>

// ---------------------------------------------------------------------------
// MixModel, 3 thread-segments/row (segment r -> output cols 12r..12r+11).
// Ladder: R1 136VGPR 127us | R2-R4 spill ~157 | R6 scalar 60VGPR 76us
//   R7 pk-f32 36VGPR 74.8us (VALU 46%, HBM 30%, occ 67% -> nothing busy)
//   R8 2 rows/thread: FAILED 85us (VGPR 64, occ 39%, +VALU from predication)
// R9: R7 body + GRID-STRIDE, 2048 blocks x 256. Theory: 11.7k short-lived
//     blocks (~1.5us each) exceed CP dispatch rate (~156 blocks/us needed) ->
//     CUs under-fed (occ 67% with no resource cap). Persistent blocks keep
//     32 waves/CU resident; waves de-stagger across iterations.
// Spill signature to watch: WRITE_SIZE >> 140,625 KB.
// ---------------------------------------------------------------------------

typedef float f2 __attribute__((ext_vector_type(2)));

__device__ __forceinline__ f2 splat2(float x) { f2 v; v.x = x; v.y = x; return v; }
__device__ __forceinline__ f2 mk2(float a, float b) { f2 v; v.x = a; v.y = b; return v; }
__device__ __forceinline__ f2 fma2(f2 a, f2 b, f2 c) { return __builtin_elementwise_fma(a, b, c); }
__device__ __forceinline__ f2 relu2(f2 a) { return __builtin_elementwise_max(a, splat2(0.0f)); }

// Packed MLP 3->3->6->3 for a pair of positions. Biases folded into first fma.
__device__ __forceinline__ void mlp_a2(f2 x0, f2 x1, f2 x2,
                                       const float* __restrict__ w0, const float* __restrict__ b0,
                                       const float* __restrict__ w1, const float* __restrict__ b1,
                                       const float* __restrict__ w2, const float* __restrict__ b2,
                                       f2& o0, f2& o1, f2& o2)
{
    f2 h0[3];
#pragma unroll
    for (int q = 0; q < 3; ++q) {
        f2 a = fma2(x0, splat2(w0[q*3+0]), splat2(b0[q]));
        a = fma2(x1, splat2(w0[q*3+1]), a);
        a = fma2(x2, splat2(w0[q*3+2]), a);
        h0[q] = relu2(a);
    }
    f2 h1[6];
#pragma unroll
    for (int q = 0; q < 6; ++q) {
        f2 a = fma2(h0[0], splat2(w1[q*3+0]), splat2(b1[q]));
        a = fma2(h0[1], splat2(w1[q*3+1]), a);
        a = fma2(h0[2], splat2(w1[q*3+2]), a);
        h1[q] = relu2(a);
    }
    f2 t[3];
#pragma unroll
    for (int q = 0; q < 3; ++q) {
        f2 a = fma2(h1[0], splat2(w2[q*6+0]), splat2(b2[q]));
#pragma unroll
        for (int i = 1; i < 6; ++i) a = fma2(h1[i], splat2(w2[q*6+i]), a);
        t[q] = a;
    }
    o0 = t[0]; o1 = t[1]; o2 = t[2];
}

// Packed MLP 4->4->6->2 for a pair of positions.
__device__ __forceinline__ void mlp_b2(f2 x0, f2 x1, f2 x2, f2 x3,
                                       const float* __restrict__ w0, const float* __restrict__ b0,
                                       const float* __restrict__ w1, const float* __restrict__ b1,
                                       const float* __restrict__ w2, const float* __restrict__ b2,
                                       f2& o0, f2& o1)
{
    f2 h0[4];
#pragma unroll
    for (int q = 0; q < 4; ++q) {
        f2 a = fma2(x0, splat2(w0[q*4+0]), splat2(b0[q]));
        a = fma2(x1, splat2(w0[q*4+1]), a);
        a = fma2(x2, splat2(w0[q*4+2]), a);
        a = fma2(x3, splat2(w0[q*4+3]), a);
        h0[q] = relu2(a);
    }
    f2 h1[6];
#pragma unroll
    for (int q = 0; q < 6; ++q) {
        f2 a = fma2(h0[0], splat2(w1[q*4+0]), splat2(b1[q]));
        a = fma2(h0[1], splat2(w1[q*4+1]), a);
        a = fma2(h0[2], splat2(w1[q*4+2]), a);
        a = fma2(h0[3], splat2(w1[q*4+3]), a);
        h1[q] = relu2(a);
    }
    f2 t[2];
#pragma unroll
    for (int q = 0; q < 2; ++q) {
        f2 a = fma2(h1[0], splat2(w2[q*6+0]), splat2(b2[q]));
#pragma unroll
        for (int i = 1; i < 6; ++i) a = fma2(h1[i], splat2(w2[q*6+i]), a);
        t[q] = a;
    }
    o0 = t[0]; o1 = t[1];
}

__global__ __launch_bounds__(256) void mixmodel_kernel(
    const float* __restrict__ u, const float* __restrict__ reg,
    const float* __restrict__ w10, const float* __restrict__ b10,
    const float* __restrict__ w11, const float* __restrict__ b11,
    const float* __restrict__ w12, const float* __restrict__ b12,
    const float* __restrict__ w20, const float* __restrict__ b20,
    const float* __restrict__ w21, const float* __restrict__ b21,
    const float* __restrict__ w22, const float* __restrict__ b22,
    const float* __restrict__ w30, const float* __restrict__ b30,
    const float* __restrict__ w31, const float* __restrict__ b31,
    const float* __restrict__ w32, const float* __restrict__ b32,
    float* __restrict__ out, int n3)
{
    const int stride = gridDim.x * blockDim.x;
    const float r0 = reg[0];
    const f2 r02 = splat2(r0);

    for (int tid = blockIdx.x * blockDim.x + threadIdx.x; tid < n3; tid += stride) {
        const int row = tid / 3;           // magic-multiply division
        const int r   = tid - 3 * row;     // 0..2 -> output cols 12r..12r+11

        const float4* __restrict__ u4 = reinterpret_cast<const float4*>(u + (size_t)row * 36);

        // ---- 20-col window: W(k) = u[row, (12r+k) mod 36], k = -4..15 ----
        float w_[20];
#pragma unroll
        for (int t = 0; t < 5; ++t) {
            int idx = 3 * r + 8 + t;               // 8..18
            if (idx >= 9) idx -= 9;                // 0..9
            if (idx >= 9) idx -= 9;                // 0..8 (double wrap)
            const float4 v = u4[idx];
            w_[4*t+0] = v.x; w_[4*t+1] = v.y; w_[4*t+2] = v.z; w_[4*t+3] = v.w;
        }
#define W(k) w_[(k) + 4]

        const float* __restrict__ rb = reg + 12 * r;

        f2 c0[2], c1[2], c2[2];   // pair P covers jj = 2P, 2P+1

        // ---- phase 1: MLP1 -> c0 ----
#pragma unroll
        for (int P = 0; P < 2; ++P) {
            const int q = 6 * P;
            f2 a0, a1, a2;
            mlp_a2(mk2(W(q - 2), W(q + 1)), mk2(W(q), W(q + 3)), mk2(W(q + 1), W(q + 4)),
                   w10, b10, w11, b11, w12, b12, a0, a1, a2);
            const f2 ua = mk2(W(q - 1), W(q + 2));
            const f2 ub = mk2(W(q + 2), W(q + 5));
            const f2 rv = mk2(rb[q + 1], rb[q + 4]);
            const f2 uv = mk2(W(q), W(q + 3));
            c0[P] = fma2(uv, rv, r02) + fma2(a2, ub, fma2(a1, ua, a0));
        }
        // ---- phase 2: MLP2 -> c1 ----
#pragma unroll
        for (int P = 0; P < 2; ++P) {
            const int q = 6 * P;
            f2 a0, a1, a2;
            mlp_a2(mk2(W(q), W(q + 3)), mk2(W(q + 1), W(q + 4)), mk2(W(q + 3), W(q + 6)),
                   w20, b20, w21, b21, w22, b22, a0, a1, a2);
            const f2 ua = mk2(W(q - 1), W(q + 2));
            const f2 ub = mk2(W(q + 2), W(q + 5));
            const f2 rv = mk2(rb[q + 2], rb[q + 5]);
            const f2 uv = mk2(W(q + 1), W(q + 4));
            c1[P] = fma2(uv, rv, r02) + fma2(a2, ub, fma2(a1, ua, a0));
        }
        // ---- phase 3: MLP3 -> c2 ----
#pragma unroll
        for (int P = 0; P < 2; ++P) {
            const int q = 6 * P;
            f2 d0, d1;
            mlp_b2(mk2(W(q), W(q + 3)), mk2(W(q + 1), W(q + 4)),
                   mk2(W(q + 3), W(q + 6)), mk2(W(q + 4), W(q + 7)),
                   w30, b30, w31, b31, w32, b32, d0, d1);
            const f2 ub = mk2(W(q + 2), W(q + 5));
            const f2 rv = mk2(rb[q + 3], rb[q + 6]);
            c2[P] = fma2(ub, rv, r02) + fma2(d1, ub, d0);
        }
#undef W

        // ---- store 12 contiguous cols at out[row, 12r..12r+11] ----
        float4* __restrict__ o4 = reinterpret_cast<float4*>(out + (size_t)row * 36 + 12 * r);
        o4[0] = make_float4(c0[0].x, c1[0].x, c2[0].x, c0[0].y);
        o4[1] = make_float4(c1[0].y, c2[0].y, c0[1].x, c1[1].x);
        o4[2] = make_float4(c2[1].x, c0[1].y, c1[1].y, c2[1].y);
    }
}

extern "C" void kernel_launch(void* const* d_in, const int* in_sizes, int n_in,
                              void* d_out, int out_size, void* d_ws, size_t ws_size,
                              hipStream_t stream)
{
    const float* u   = (const float*)d_in[1];
    const float* reg = (const float*)d_in[2];
    const float* w10 = (const float*)d_in[3];
    const float* b10 = (const float*)d_in[4];
    const float* w11 = (const float*)d_in[5];
    const float* b11 = (const float*)d_in[6];
    const float* w12 = (const float*)d_in[7];
    const float* b12 = (const float*)d_in[8];
    const float* w20 = (const float*)d_in[9];
    const float* b20 = (const float*)d_in[10];
    const float* w21 = (const float*)d_in[11];
    const float* b21 = (const float*)d_in[12];
    const float* w22 = (const float*)d_in[13];
    const float* b22 = (const float*)d_in[14];
    const float* w30 = (const float*)d_in[15];
    const float* b30 = (const float*)d_in[16];
    const float* w31 = (const float*)d_in[17];
    const float* b31 = (const float*)d_in[18];
    const float* w32 = (const float*)d_in[19];
    const float* b32 = (const float*)d_in[20];
    float* out = (float*)d_out;

    const int n  = in_sizes[1] / 36;   // 1,000,000 rows
    const int n3 = 3 * n;              // 3 segments per row
    const int block = 256;
    const int grid = 2048;             // persistent blocks; grid-stride

    hipLaunchKernelGGL(mixmodel_kernel, dim3(grid), dim3(block), 0, stream,
                       u, reg, w10, b10, w11, b11, w12, b12,
                       w20, b20, w21, b21, w22, b22,
                       w30, b30, w31, b31, w32, b32, out, n3);
}

// Round 10
// 71.053 us; speedup vs baseline: 1.3344x; 1.3344x over previous
//
#include <hip/hip_runtime.h>

// ---------------------------------------------------------------------------
// MixModel, 3 thread-segments/row, LDS-staged u-tile.
// Ladder: R1 136VGPR 127us | R2-R4 spill ~157 | R6 scalar 60VGPR 76us
//   R7 pk-f32 36VGPR 74.8us (VALU 46%, HBM 30%, occ 67% -> latency, lockstep)
//   R8 2rows/thr 85us (VGPR 64 -> occ tier halved)
//   R9 grid-stride 94.8us (compiler pipelined loop -> VGPR 68 -> occ 29%)
// Lesson: any per-thread ILP scheme busts the <=48 VGPR occupancy budget.
// R10: block-level pipelining instead. 192-thr block (3 waves) stages its
//   64-row u-tile (9216 B) via global_load_lds dwordx4 (contiguous DMA, no
//   VGPR roundtrip), barrier, then threads read 20-float windows from LDS
//   (5x ds_read_b128) + reg[] from LDS (broadcast reads). Per-thread regs
//   unchanged from R7 (~40): occupancy stays high; staggered blocks overlap
//   DMA of one block with compute of others (canonical GEMM staging).
// Spill signature: WRITE_SIZE >> 140,625 KB.  n=1e6 = 15625 x 64 rows exact.
// ---------------------------------------------------------------------------

typedef float f2 __attribute__((ext_vector_type(2)));

__device__ __forceinline__ f2 splat2(float x) { f2 v; v.x = x; v.y = x; return v; }
__device__ __forceinline__ f2 mk2(float a, float b) { f2 v; v.x = a; v.y = b; return v; }
__device__ __forceinline__ f2 fma2(f2 a, f2 b, f2 c) { return __builtin_elementwise_fma(a, b, c); }
__device__ __forceinline__ f2 relu2(f2 a) { return __builtin_elementwise_max(a, splat2(0.0f)); }

// Packed MLP 3->3->6->3 for a pair of positions. Biases folded into first fma.
__device__ __forceinline__ void mlp_a2(f2 x0, f2 x1, f2 x2,
                                       const float* __restrict__ w0, const float* __restrict__ b0,
                                       const float* __restrict__ w1, const float* __restrict__ b1,
                                       const float* __restrict__ w2, const float* __restrict__ b2,
                                       f2& o0, f2& o1, f2& o2)
{
    f2 h0[3];
#pragma unroll
    for (int q = 0; q < 3; ++q) {
        f2 a = fma2(x0, splat2(w0[q*3+0]), splat2(b0[q]));
        a = fma2(x1, splat2(w0[q*3+1]), a);
        a = fma2(x2, splat2(w0[q*3+2]), a);
        h0[q] = relu2(a);
    }
    f2 h1[6];
#pragma unroll
    for (int q = 0; q < 6; ++q) {
        f2 a = fma2(h0[0], splat2(w1[q*3+0]), splat2(b1[q]));
        a = fma2(h0[1], splat2(w1[q*3+1]), a);
        a = fma2(h0[2], splat2(w1[q*3+2]), a);
        h1[q] = relu2(a);
    }
    f2 t[3];
#pragma unroll
    for (int q = 0; q < 3; ++q) {
        f2 a = fma2(h1[0], splat2(w2[q*6+0]), splat2(b2[q]));
#pragma unroll
        for (int i = 1; i < 6; ++i) a = fma2(h1[i], splat2(w2[q*6+i]), a);
        t[q] = a;
    }
    o0 = t[0]; o1 = t[1]; o2 = t[2];
}

// Packed MLP 4->4->6->2 for a pair of positions.
__device__ __forceinline__ void mlp_b2(f2 x0, f2 x1, f2 x2, f2 x3,
                                       const float* __restrict__ w0, const float* __restrict__ b0,
                                       const float* __restrict__ w1, const float* __restrict__ b1,
                                       const float* __restrict__ w2, const float* __restrict__ b2,
                                       f2& o0, f2& o1)
{
    f2 h0[4];
#pragma unroll
    for (int q = 0; q < 4; ++q) {
        f2 a = fma2(x0, splat2(w0[q*4+0]), splat2(b0[q]));
        a = fma2(x1, splat2(w0[q*4+1]), a);
        a = fma2(x2, splat2(w0[q*4+2]), a);
        a = fma2(x3, splat2(w0[q*4+3]), a);
        h0[q] = relu2(a);
    }
    f2 h1[6];
#pragma unroll
    for (int q = 0; q < 6; ++q) {
        f2 a = fma2(h0[0], splat2(w1[q*4+0]), splat2(b1[q]));
        a = fma2(h0[1], splat2(w1[q*4+1]), a);
        a = fma2(h0[2], splat2(w1[q*4+2]), a);
        a = fma2(h0[3], splat2(w1[q*4+3]), a);
        h1[q] = relu2(a);
    }
    f2 t[2];
#pragma unroll
    for (int q = 0; q < 2; ++q) {
        f2 a = fma2(h1[0], splat2(w2[q*6+0]), splat2(b2[q]));
#pragma unroll
        for (int i = 1; i < 6; ++i) a = fma2(h1[i], splat2(w2[q*6+i]), a);
        t[q] = a;
    }
    o0 = t[0]; o1 = t[1];
}

#define ROWS_PB 64
#define TPB 192   // 3 waves; ROWS_PB*9 f4 chunks = 576 = 3*TPB

__global__ __launch_bounds__(TPB) void mixmodel_kernel(
    const float* __restrict__ u, const float* __restrict__ reg,
    const float* __restrict__ w10, const float* __restrict__ b10,
    const float* __restrict__ w11, const float* __restrict__ b11,
    const float* __restrict__ w12, const float* __restrict__ b12,
    const float* __restrict__ w20, const float* __restrict__ b20,
    const float* __restrict__ w21, const float* __restrict__ b21,
    const float* __restrict__ w22, const float* __restrict__ b22,
    const float* __restrict__ w30, const float* __restrict__ b30,
    const float* __restrict__ w31, const float* __restrict__ b31,
    const float* __restrict__ w32, const float* __restrict__ b32,
    float* __restrict__ out, int n)
{
    __shared__ float4 s4[ROWS_PB * 9];   // 9216 B u-tile
    __shared__ float  sreg[37];

    const int brow = blockIdx.x * ROWS_PB;

    // ---- stage 64-row u-tile via DMA: wave-uniform LDS base + lane*16 ----
    {
        const float4* __restrict__ g = reinterpret_cast<const float4*>(u + (size_t)brow * 36);
        const int wid  = threadIdx.x >> 6;
        const int lane = threadIdx.x & 63;
#pragma unroll
        for (int w = 0; w < 3; ++w) {
            const int base = w * TPB + wid * 64;   // f4 units, wave-uniform
            __builtin_amdgcn_global_load_lds(
                (const __attribute__((address_space(1))) void*)(g + base + lane),
                (__attribute__((address_space(3))) void*)(s4 + base),
                16, 0, 0);
        }
    }
    if (threadIdx.x < 37) sreg[threadIdx.x] = reg[threadIdx.x];
    asm volatile("s_waitcnt vmcnt(0)" ::: "memory");
    __syncthreads();

    const int rl = threadIdx.x / 3;          // row within tile, 0..63
    const int r  = threadIdx.x - 3 * rl;     // 0..2 -> output cols 12r..12r+11
    const int row = brow + rl;
    if (row >= n) return;

    // ---- 20-col window from LDS: W(k) = u[row, (12r+k) mod 36], k=-4..15 ----
    float w_[20];
#pragma unroll
    for (int t = 0; t < 5; ++t) {
        int idx = 3 * r + 8 + t;               // 8..18
        if (idx >= 9) idx -= 9;                // 0..9
        if (idx >= 9) idx -= 9;                // 0..8 (double wrap)
        const float4 v = s4[rl * 9 + idx];
        w_[4*t+0] = v.x; w_[4*t+1] = v.y; w_[4*t+2] = v.z; w_[4*t+3] = v.w;
    }
#define W(k) w_[(k) + 4]

    const f2 r02 = splat2(sreg[0]);
    const float* rb = sreg + 12 * r;          // LDS, broadcast reads

    f2 c0[2], c1[2], c2[2];   // pair P covers jj = 2P, 2P+1

    // ---- phase 1: MLP1 -> c0 ----
#pragma unroll
    for (int P = 0; P < 2; ++P) {
        const int q = 6 * P;
        f2 a0, a1, a2;
        mlp_a2(mk2(W(q - 2), W(q + 1)), mk2(W(q), W(q + 3)), mk2(W(q + 1), W(q + 4)),
               w10, b10, w11, b11, w12, b12, a0, a1, a2);
        const f2 ua = mk2(W(q - 1), W(q + 2));
        const f2 ub = mk2(W(q + 2), W(q + 5));
        const f2 rv = mk2(rb[q + 1], rb[q + 4]);
        const f2 uv = mk2(W(q), W(q + 3));
        c0[P] = fma2(uv, rv, r02) + fma2(a2, ub, fma2(a1, ua, a0));
    }
    // ---- phase 2: MLP2 -> c1 ----
#pragma unroll
    for (int P = 0; P < 2; ++P) {
        const int q = 6 * P;
        f2 a0, a1, a2;
        mlp_a2(mk2(W(q), W(q + 3)), mk2(W(q + 1), W(q + 4)), mk2(W(q + 3), W(q + 6)),
               w20, b20, w21, b21, w22, b22, a0, a1, a2);
        const f2 ua = mk2(W(q - 1), W(q + 2));
        const f2 ub = mk2(W(q + 2), W(q + 5));
        const f2 rv = mk2(rb[q + 2], rb[q + 5]);
        const f2 uv = mk2(W(q + 1), W(q + 4));
        c1[P] = fma2(uv, rv, r02) + fma2(a2, ub, fma2(a1, ua, a0));
    }
    // ---- phase 3: MLP3 -> c2 ----
#pragma unroll
    for (int P = 0; P < 2; ++P) {
        const int q = 6 * P;
        f2 d0, d1;
        mlp_b2(mk2(W(q), W(q + 3)), mk2(W(q + 1), W(q + 4)),
               mk2(W(q + 3), W(q + 6)), mk2(W(q + 4), W(q + 7)),
               w30, b30, w31, b31, w32, b32, d0, d1);
        const f2 ub = mk2(W(q + 2), W(q + 5));
        const f2 rv = mk2(rb[q + 3], rb[q + 6]);
        c2[P] = fma2(ub, rv, r02) + fma2(d1, ub, d0);
    }
#undef W

    // ---- store 12 contiguous cols at out[row, 12r..12r+11] ----
    float4* __restrict__ o4 = reinterpret_cast<float4*>(out + (size_t)row * 36 + 12 * r);
    o4[0] = make_float4(c0[0].x, c1[0].x, c2[0].x, c0[0].y);
    o4[1] = make_float4(c1[0].y, c2[0].y, c0[1].x, c1[1].x);
    o4[2] = make_float4(c2[1].x, c0[1].y, c1[1].y, c2[1].y);
}

extern "C" void kernel_launch(void* const* d_in, const int* in_sizes, int n_in,
                              void* d_out, int out_size, void* d_ws, size_t ws_size,
                              hipStream_t stream)
{
    const float* u   = (const float*)d_in[1];
    const float* reg = (const float*)d_in[2];
    const float* w10 = (const float*)d_in[3];
    const float* b10 = (const float*)d_in[4];
    const float* w11 = (const float*)d_in[5];
    const float* b11 = (const float*)d_in[6];
    const float* w12 = (const float*)d_in[7];
    const float* b12 = (const float*)d_in[8];
    const float* w20 = (const float*)d_in[9];
    const float* b20 = (const float*)d_in[10];
    const float* w21 = (const float*)d_in[11];
    const float* b21 = (const float*)d_in[12];
    const float* w22 = (const float*)d_in[13];
    const float* b22 = (const float*)d_in[14];
    const float* w30 = (const float*)d_in[15];
    const float* b30 = (const float*)d_in[16];
    const float* w31 = (const float*)d_in[17];
    const float* b31 = (const float*)d_in[18];
    const float* w32 = (const float*)d_in[19];
    const float* b32 = (const float*)d_in[20];
    float* out = (float*)d_out;

    const int n = in_sizes[1] / 36;            // 1,000,000 rows; 64 | n exactly
    const int grid = (n + ROWS_PB - 1) / ROWS_PB;   // 15625 full tiles

    hipLaunchKernelGGL(mixmodel_kernel, dim3(grid), dim3(TPB), 0, stream,
                       u, reg, w10, b10, w11, b11, w12, b12,
                       w20, b20, w21, b21, w22, b22,
                       w30, b30, w31, b31, w32, b32, out, n);
}